// Round 12
// baseline (94.348 us; speedup 1.0000x reference)
//
#include <hip/hip_runtime.h>

// ---------------------------------------------------------------------------
// AI4Urban one-timestep NS solver on 64x128x256, f32.  Round 12:
//  = R11 (88.9us) with k_down+k_upf fused into k_mgall WITHOUT a grid
//  barrier: each of the 64 blocks recomputes the coarse-pyramid REGION it
//  needs (r2 12x16x24, r3 6x8x12, r4 3x4x6 in LDS, ~26KB) straight from
//  global r1.  Redundant coarse compute is trivial; r1 re-reads L2-resident.
//  r2/r3 never hit global; r4 own-tile still written (O_r output, iter 1).
//  7 dispatches.
// ---------------------------------------------------------------------------

constexpr int NZ = 64, NY = 128, NX = 256;
constexpr int NTOT = NZ * NY * NX;
constexpr float DT  = 0.01f;
constexpr float RDT = 100.0f;          // 1/DT
constexpr float RE  = 0.001f;
constexpr float UBC = -1.0f;
constexpr float SIXTH = 1.0f / 6.0f;
constexpr float IDIAG = -1.0f / 6.0f;  // 1/DIAG, DIAG=-6

__device__ __forceinline__ float frcp(float x) { return __builtin_amdgcn_rcpf(x); }

__device__ __forceinline__ int idx3(int z, int y, int x) {
    return (z * NY + y) * NX + x;
}

union F4 { float4 v; float f[4]; };

__device__ __forceinline__ float4 ld4(const float* __restrict__ f, int z, int y, int x0) {
    return *reinterpret_cast<const float4*>(&f[idx3(z, y, x0)]);
}
__device__ __forceinline__ void st4(float* __restrict__ f, int c, const F4& a) {
    *reinterpret_cast<float4*>(&f[c]) = a.v;
}
__device__ __forceinline__ float4 ldsrow(const float* r, int x0) {
    return *reinterpret_cast<const float4*>(&r[x0]);
}

__device__ __forceinline__ void zero4(float o[4]) {
    #pragma unroll
    for (int i = 0; i < 4; i++) o[i] = 0.f;
}

__device__ __forceinline__ void row0(const float* __restrict__ f, int z, int y, int x0,
                                     bool ok, float o[4]) {
    if (ok) { F4 a; a.v = ld4(f, z, y, x0);
        #pragma unroll
        for (int i = 0; i < 4; i++) o[i] = a.f[i];
    } else {
        zero4(o);
    }
}
__device__ __forceinline__ void row3s(const float* __restrict__ u, const float* __restrict__ v,
                                      const float* __restrict__ w, const float* __restrict__ sg,
                                      int z, int y, int x0, bool ok,
                                      float uo[4], float vo[4], float wo[4]) {
    if (ok) {
        F4 a, b, c, s;
        a.v = ld4(u, z, y, x0); b.v = ld4(v, z, y, x0);
        c.v = ld4(w, z, y, x0); s.v = ld4(sg, z, y, x0);
        #pragma unroll
        for (int i = 0; i < 4; i++) {
            float iv = frcp(1.f + DT * s.f[i]);
            uo[i] = a.f[i] * iv; vo[i] = b.f[i] * iv; wo[i] = c.f[i] * iv;
        }
    } else {
        zero4(uo); zero4(vo); zero4(wo);
    }
}

// XCD z-slab swizzle decode: 2048 blocks, block (64,4).
__device__ __forceinline__ void decode_f(int d, int& y, int& z) {
    int k = d & 7, j = d >> 3;
    z = 8 * k + (j >> 5);
    y = (j & 31) * 4 + threadIdx.y;
}
// 1024 blocks, block (64,4,2): XCD k owns ztile in [4k,4k+4).
__device__ __forceinline__ void decode_f2(int d, int& y, int& z, int& ytile, int& ztile) {
    int k = d & 7, j = d >> 3;
    ztile = 4 * k + (j >> 5);
    ytile = j & 31;
    z = ztile * 2 + threadIdx.z;
    y = ytile * 4 + threadIdx.y;
}

// K1: predictor, solid_body fused; LDS row-sharing across the 4-y block
__global__ __launch_bounds__(256) void k_predict(
    const float* __restrict__ u, const float* __restrict__ v, const float* __restrict__ w,
    const float* __restrict__ p, const float* __restrict__ sg,
    float* __restrict__ bu, float* __restrict__ bv, float* __restrict__ bw) {
    __shared__ __align__(16) float su[6][256], sv[6][256], sw[6][256], sp[6][256];
    int tx = threadIdx.x, ty = threadIdx.y, y, z;
    decode_f(blockIdx.x, y, z);
    int x0 = tx << 2, c = idx3(z, y, x0);

    F4 sc; sc.v = ld4(sg, z, y, x0);
    F4 u4, v4, w4; u4.v = ld4(u, z, y, x0); v4.v = ld4(v, z, y, x0); w4.v = ld4(w, z, y, x0);
    F4 pc; pc.v = ld4(p, z, y, x0);
    float inv[4], uc[4], vc[4], wc[4];
    #pragma unroll
    for (int i = 0; i < 4; i++) {
        inv[i] = frcp(1.f + DT * sc.f[i]);
        uc[i] = u4.f[i] * inv[i]; vc[i] = v4.f[i] * inv[i]; wc[i] = w4.f[i] * inv[i];
        su[ty + 1][x0 + i] = uc[i]; sv[ty + 1][x0 + i] = vc[i];
        sw[ty + 1][x0 + i] = wc[i]; sp[ty + 1][x0 + i] = pc.f[i];
    }
    if (ty == 0) {
        int ym = y - 1;
        if (ym >= 0) {
            F4 a, b, c2, s;
            a.v = ld4(u, z, ym, x0); b.v = ld4(v, z, ym, x0);
            c2.v = ld4(w, z, ym, x0); s.v = ld4(sg, z, ym, x0);
            #pragma unroll
            for (int i = 0; i < 4; i++) {
                float iv = frcp(1.f + DT * s.f[i]);
                su[0][x0 + i] = a.f[i] * iv; sv[0][x0 + i] = b.f[i] * iv;
                sw[0][x0 + i] = c2.f[i] * iv;
            }
        } else {
            #pragma unroll
            for (int i = 0; i < 4; i++) { su[0][x0+i] = 0.f; sv[0][x0+i] = 0.f; sw[0][x0+i] = 0.f; }
        }
        F4 pp; pp.v = ld4(p, z, ym >= 0 ? ym : 0, x0);
        #pragma unroll
        for (int i = 0; i < 4; i++) sp[0][x0 + i] = pp.f[i];
    } else if (ty == 3) {
        int yp = y + 1;
        if (yp < NY) {
            F4 a, b, c2, s;
            a.v = ld4(u, z, yp, x0); b.v = ld4(v, z, yp, x0);
            c2.v = ld4(w, z, yp, x0); s.v = ld4(sg, z, yp, x0);
            #pragma unroll
            for (int i = 0; i < 4; i++) {
                float iv = frcp(1.f + DT * s.f[i]);
                su[5][x0 + i] = a.f[i] * iv; sv[5][x0 + i] = b.f[i] * iv;
                sw[5][x0 + i] = c2.f[i] * iv;
            }
        } else {
            #pragma unroll
            for (int i = 0; i < 4; i++) { su[5][x0+i] = 0.f; sv[5][x0+i] = 0.f; sw[5][x0+i] = 0.f; }
        }
        F4 pp; pp.v = ld4(p, z, yp < NY ? yp : NY - 1, x0);
        #pragma unroll
        for (int i = 0; i < 4; i++) sp[5][x0 + i] = pp.f[i];
    }
    __syncthreads();

    F4 Uym, Uyp, Vym, Vyp, Wym, Wyp, Pym, Pyp;
    Uym.v = ldsrow(su[ty], x0);     Uyp.v = ldsrow(su[ty + 2], x0);
    Vym.v = ldsrow(sv[ty], x0);     Vyp.v = ldsrow(sv[ty + 2], x0);
    Wym.v = ldsrow(sw[ty], x0);     Wyp.v = ldsrow(sw[ty + 2], x0);
    Pym.v = ldsrow(sp[ty], x0);     Pyp.v = ldsrow(sp[ty + 2], x0);

    float uzm[4], vzm[4], wzm[4], uzp[4], vzp[4], wzp[4];
    row3s(u, v, w, sg, z - 1, y, x0, z > 0,      uzm, vzm, wzm);
    row3s(u, v, w, sg, z + 1, y, x0, z < NZ - 1, uzp, vzp, wzp);
    F4 pzm, pzp;
    pzm.v = ld4(p, z > 0 ? z - 1 : 0, y, x0);
    pzp.v = ld4(p, z < NZ - 1 ? z + 1 : z, y, x0);

    float uxmS = tx ? su[ty + 1][x0 - 1] : UBC;
    float vxmS = tx ? sv[ty + 1][x0 - 1] : 0.f;
    float wxmS = tx ? sw[ty + 1][x0 - 1] : 0.f;
    float uxpS = (tx < 63) ? su[ty + 1][x0 + 4] : 0.f;
    float vxpS = (tx < 63) ? sv[ty + 1][x0 + 4] : 0.f;
    float wxpS = (tx < 63) ? sw[ty + 1][x0 + 4] : 0.f;
    float pxmS = tx ? sp[ty + 1][x0 - 1] : pc.f[0];
    float pxpS = (tx < 63) ? sp[ty + 1][x0 + 4] : pc.f[3];

    F4 obu, obv, obw;
    #pragma unroll
    for (int i = 0; i < 4; i++) {
        float uxm = i ? uc[i - 1] : uxmS, uxp = (i < 3) ? uc[i + 1] : uxpS;
        float vxm = i ? vc[i - 1] : vxmS, vxp = (i < 3) ? vc[i + 1] : vxpS;
        float wxm = i ? wc[i - 1] : wxmS, wxp = (i < 3) ? wc[i + 1] : wxpS;
        float pxm = i ? pc.f[i - 1] : pxmS, pxp = (i < 3) ? pc.f[i + 1] : pxpS;
        float dpx = 0.5f * (pxp - pxm);
        float dpy = 0.5f * (Pyp.f[i] - Pym.f[i]);
        float dpz = 0.5f * (pzp.f[i] - pzm.f[i]);
        float lap_u = uxm + uxp + Uym.f[i] + Uyp.f[i] + uzm[i] + uzp[i] - 6.f * uc[i];
        float lap_v = vxm + vxp + Vym.f[i] + Vyp.f[i] + vzm[i] + vzp[i] - 6.f * vc[i];
        float lap_w = wxm + wxp + Wym.f[i] + Wyp.f[i] + wzm[i] + wzp[i] - 6.f * wc[i];
        float bun = uc[i] + 0.5f * (RE * lap_u * DT
                    - uc[i] * (0.5f * (uxp - uxm)) * DT
                    - vc[i] * (0.5f * (Uyp.f[i] - Uym.f[i])) * DT
                    - wc[i] * (0.5f * (uzp[i] - uzm[i])) * DT) - dpx * DT;
        float bvn = vc[i] + 0.5f * (RE * lap_v * DT
                    - uc[i] * (0.5f * (vxp - vxm)) * DT
                    - vc[i] * (0.5f * (Vyp.f[i] - Vym.f[i])) * DT
                    - wc[i] * (0.5f * (vzp[i] - vzm[i])) * DT) - dpy * DT;
        float bwn = wc[i] + 0.5f * (RE * lap_w * DT
                    - uc[i] * (0.5f * (wxp - wxm)) * DT
                    - vc[i] * (0.5f * (Wyp.f[i] - Wym.f[i])) * DT
                    - wc[i] * (0.5f * (wzp[i] - wzm[i])) * DT) - dpz * DT;
        obu.f[i] = bun * inv[i];
        obv.f[i] = bvn * inv[i];
        obw.f[i] = bwn * inv[i];
    }
    st4(bu, c, obu); st4(bv, c, obv); st4(bw, c, obw);
}

// K2: corrector; LDS row-sharing of bu/bv/bw and p
__global__ __launch_bounds__(256) void k_correct(
    const float* __restrict__ u, const float* __restrict__ v, const float* __restrict__ w,
    const float* __restrict__ sg,
    const float* __restrict__ bu, const float* __restrict__ bv, const float* __restrict__ bw,
    const float* __restrict__ p,
    float* __restrict__ u2, float* __restrict__ v2, float* __restrict__ w2) {
    __shared__ __align__(16) float su[6][256], sv[6][256], sw[6][256], sp[6][256];
    int tx = threadIdx.x, ty = threadIdx.y, y, z;
    decode_f(blockIdx.x, y, z);
    int x0 = tx << 2, c = idx3(z, y, x0);

    F4 sc; sc.v = ld4(sg, z, y, x0);
    F4 u4, v4, w4; u4.v = ld4(u, z, y, x0); v4.v = ld4(v, z, y, x0); w4.v = ld4(w, z, y, x0);
    F4 buc, bvc, bwc; buc.v = ld4(bu, z, y, x0); bvc.v = ld4(bv, z, y, x0); bwc.v = ld4(bw, z, y, x0);
    F4 pc; pc.v = ld4(p, z, y, x0);
    #pragma unroll
    for (int i = 0; i < 4; i++) {
        su[ty + 1][x0 + i] = buc.f[i]; sv[ty + 1][x0 + i] = bvc.f[i];
        sw[ty + 1][x0 + i] = bwc.f[i]; sp[ty + 1][x0 + i] = pc.f[i];
    }
    if (ty == 0) {
        int ym = y - 1;
        if (ym >= 0) {
            F4 a, b, c2;
            a.v = ld4(bu, z, ym, x0); b.v = ld4(bv, z, ym, x0); c2.v = ld4(bw, z, ym, x0);
            #pragma unroll
            for (int i = 0; i < 4; i++) { su[0][x0+i] = a.f[i]; sv[0][x0+i] = b.f[i]; sw[0][x0+i] = c2.f[i]; }
        } else {
            #pragma unroll
            for (int i = 0; i < 4; i++) { su[0][x0+i] = 0.f; sv[0][x0+i] = 0.f; sw[0][x0+i] = 0.f; }
        }
        F4 pp; pp.v = ld4(p, z, ym >= 0 ? ym : 0, x0);
        #pragma unroll
        for (int i = 0; i < 4; i++) sp[0][x0 + i] = pp.f[i];
    } else if (ty == 3) {
        int yp = y + 1;
        if (yp < NY) {
            F4 a, b, c2;
            a.v = ld4(bu, z, yp, x0); b.v = ld4(bv, z, yp, x0); c2.v = ld4(bw, z, yp, x0);
            #pragma unroll
            for (int i = 0; i < 4; i++) { su[5][x0+i] = a.f[i]; sv[5][x0+i] = b.f[i]; sw[5][x0+i] = c2.f[i]; }
        } else {
            #pragma unroll
            for (int i = 0; i < 4; i++) { su[5][x0+i] = 0.f; sv[5][x0+i] = 0.f; sw[5][x0+i] = 0.f; }
        }
        F4 pp; pp.v = ld4(p, z, yp < NY ? yp : NY - 1, x0);
        #pragma unroll
        for (int i = 0; i < 4; i++) sp[5][x0 + i] = pp.f[i];
    }
    __syncthreads();

    F4 Uym, Uyp, Vym, Vyp, Wym, Wyp, Pym, Pyp;
    Uym.v = ldsrow(su[ty], x0);     Uyp.v = ldsrow(su[ty + 2], x0);
    Vym.v = ldsrow(sv[ty], x0);     Vyp.v = ldsrow(sv[ty + 2], x0);
    Wym.v = ldsrow(sw[ty], x0);     Wyp.v = ldsrow(sw[ty + 2], x0);
    Pym.v = ldsrow(sp[ty], x0);     Pyp.v = ldsrow(sp[ty + 2], x0);

    float uzm[4], vzm[4], wzm[4], uzp[4], vzp[4], wzp[4];
    row0(bu, z - 1, y, x0, z > 0, uzm);      row0(bv, z - 1, y, x0, z > 0, vzm);
    row0(bw, z - 1, y, x0, z > 0, wzm);
    row0(bu, z + 1, y, x0, z < NZ - 1, uzp); row0(bv, z + 1, y, x0, z < NZ - 1, vzp);
    row0(bw, z + 1, y, x0, z < NZ - 1, wzp);
    F4 pzm, pzp;
    pzm.v = ld4(p, z > 0 ? z - 1 : 0, y, x0);
    pzp.v = ld4(p, z < NZ - 1 ? z + 1 : z, y, x0);

    float uxmS = tx ? su[ty + 1][x0 - 1] : UBC;
    float vxmS = tx ? sv[ty + 1][x0 - 1] : 0.f;
    float wxmS = tx ? sw[ty + 1][x0 - 1] : 0.f;
    float uxpS = (tx < 63) ? su[ty + 1][x0 + 4] : 0.f;
    float vxpS = (tx < 63) ? sv[ty + 1][x0 + 4] : 0.f;
    float wxpS = (tx < 63) ? sw[ty + 1][x0 + 4] : 0.f;
    float pxmS = tx ? sp[ty + 1][x0 - 1] : pc.f[0];
    float pxpS = (tx < 63) ? sp[ty + 1][x0 + 4] : pc.f[3];

    F4 ou, ov, ow;
    #pragma unroll
    for (int i = 0; i < 4; i++) {
        float inv = frcp(1.f + DT * sc.f[i]);
        float u1c = u4.f[i] * inv, v1c = v4.f[i] * inv, w1c = w4.f[i] * inv;
        float uxm = i ? buc.f[i - 1] : uxmS, uxp = (i < 3) ? buc.f[i + 1] : uxpS;
        float vxm = i ? bvc.f[i - 1] : vxmS, vxp = (i < 3) ? bvc.f[i + 1] : vxpS;
        float wxm = i ? bwc.f[i - 1] : wxmS, wxp = (i < 3) ? bwc.f[i + 1] : wxpS;
        float pxm = i ? pc.f[i - 1] : pxmS, pxp = (i < 3) ? pc.f[i + 1] : pxpS;
        float dpx = 0.5f * (pxp - pxm);
        float dpy = 0.5f * (Pyp.f[i] - Pym.f[i]);
        float dpz = 0.5f * (pzp.f[i] - pzm.f[i]);
        float lap_u = uxm + uxp + Uym.f[i] + Uyp.f[i] + uzm[i] + uzp[i] - 6.f * buc.f[i];
        float lap_v = vxm + vxp + Vym.f[i] + Vyp.f[i] + vzm[i] + vzp[i] - 6.f * bvc.f[i];
        float lap_w = wxm + wxp + Wym.f[i] + Wyp.f[i] + wzm[i] + wzp[i] - 6.f * bwc.f[i];
        float un = u1c + RE * lap_u * DT
                   - buc.f[i] * (0.5f * (uxp - uxm)) * DT
                   - bvc.f[i] * (0.5f * (Uyp.f[i] - Uym.f[i])) * DT
                   - bwc.f[i] * (0.5f * (uzp[i] - uzm[i])) * DT - dpx * DT;
        float vn = v1c + RE * lap_v * DT
                   - buc.f[i] * (0.5f * (vxp - vxm)) * DT
                   - bvc.f[i] * (0.5f * (Vyp.f[i] - Vym.f[i])) * DT
                   - bwc.f[i] * (0.5f * (vzp[i] - vzm[i])) * DT - dpy * DT;
        float wn = w1c + RE * lap_w * DT
                   - buc.f[i] * (0.5f * (wxp - wxm)) * DT
                   - bvc.f[i] * (0.5f * (Wyp.f[i] - Wym.f[i])) * DT
                   - bwc.f[i] * (0.5f * (wzp[i] - wzm[i])) * DT - dpz * DT;
        ou.f[i] = un * inv; ov.f[i] = vn * inv; ow.f[i] = wn * inv;
    }
    st4(u2, c, ou); st4(v2, c, ov); st4(w2, c, ow);
}

// K3: r0 = lap_ep(p) - b (b inline), plus fused level-0->1 restriction of r0.
__global__ __launch_bounds__(512) void k_divresid_r(
    const float* __restrict__ u2, const float* __restrict__ v2, const float* __restrict__ w2,
    const float* __restrict__ p, float* __restrict__ r0, float* __restrict__ r1) {
    __shared__ float lds[2][4][256];
    int tx = threadIdx.x, ty = threadIdx.y, tz = threadIdx.z;
    int y, z, ytile, ztile;
    decode_f2(blockIdx.x, y, z, ytile, ztile);
    int x0 = tx << 2, c = idx3(z, y, x0);

    F4 uc; uc.v = ld4(u2, z, y, x0);
    float uxmS = tx ? u2[c - 1] : UBC, uxpS = (tx < 63) ? u2[c + 4] : 0.f;
    float vym[4], vyp[4], wzm[4], wzp[4];
    row0(v2, z, y - 1, x0, y > 0, vym);
    row0(v2, z, y + 1, x0, y < NY - 1, vyp);
    row0(w2, z - 1, y, x0, z > 0, wzm);
    row0(w2, z + 1, y, x0, z < NZ - 1, wzp);

    F4 pc, pym, pyp, pzm, pzp;
    pc.v  = ld4(p, z, y, x0);
    pym.v = ld4(p, z, y > 0 ? y - 1 : 0, x0);
    pyp.v = ld4(p, z, y < NY - 1 ? y + 1 : y, x0);
    pzm.v = ld4(p, z > 0 ? z - 1 : 0, y, x0);
    pzp.v = ld4(p, z < NZ - 1 ? z + 1 : z, y, x0);
    float pxmS = tx ? p[c - 1] : pc.f[0];
    float pxpS = (tx < 63) ? p[c + 4] : pc.f[3];

    F4 o;
    #pragma unroll
    for (int i = 0; i < 4; i++) {
        float uxm = i ? uc.f[i - 1] : uxmS, uxp = (i < 3) ? uc.f[i + 1] : uxpS;
        float bval = -(0.5f * (uxp - uxm) + 0.5f * (vyp[i] - vym[i])
                       + 0.5f * (wzp[i] - wzm[i])) * RDT;
        float pxm = i ? pc.f[i - 1] : pxmS, pxp = (i < 3) ? pc.f[i + 1] : pxpS;
        float lap = pxm + pxp + pym.f[i] + pyp.f[i] + pzm.f[i] + pzp.f[i] - 6.f * pc.f[i];
        o.f[i] = lap - bval;
    }
    st4(r0, c, o);
    *reinterpret_cast<float4*>(&lds[tz][ty][x0]) = o.v;
    __syncthreads();
    int tid = (tz * 4 + ty) * 64 + tx;
    if (tid < 256) {
        int y1loc = tid >> 7, x1 = tid & 127;
        int xf = x1 << 1, yf = y1loc << 1;
        float s = lds[0][yf][xf]     + lds[0][yf][xf + 1]
                + lds[0][yf + 1][xf] + lds[0][yf + 1][xf + 1]
                + lds[1][yf][xf]     + lds[1][yf][xf + 1]
                + lds[1][yf + 1][xf] + lds[1][yf + 1][xf + 1];
        int y1 = ytile * 2 + y1loc, z1 = ztile;
        r1[(z1 * 64 + y1) * 128 + x1] = 0.125f * s;
    }
}

// K4: fused MG coarse chain, barrier-free: each block recomputes its own
// r2/r3/r4 regions in LDS from global r1, then runs the up-chain B->C->D.
// grid(4,4,4), block 512.  Also writes the block's own r4 tile to r4out.
__global__ __launch_bounds__(512) void k_mgall(const float* __restrict__ r1,
    float* __restrict__ r4out, float* __restrict__ D) {
    __shared__ float R2[12][16][24];   // z2 in [4bz-4,4bz+8)
    __shared__ float R3[6][8][12];     // z3 in [2bz-2,2bz+4)
    __shared__ float R4[3][4][6];      // z4 in [bz-1,bz+2)
    __shared__ float Bl[4][6][10];
    __shared__ float Cl[6][10][18];
    int tid = threadIdx.x;
    int bx = blockIdx.x, by = blockIdx.y, bz = blockIdx.z;
    int z2b = 4 * bz - 4, y2b = 8 * by - 4, x2b = 16 * bx - 4;
    int z3b = 2 * bz - 2, y3b = 4 * by - 2, x3b = 8 * bx - 2;
    int z4b = bz - 1,     y4b = 2 * by - 1, x4b = 4 * bx - 1;

    // Phase 1: r2 region from global r1 (12*16*24 = 4608)
    for (int i = tid; i < 4608; i += 512) {
        int lx = i % 24, ly = (i / 24) % 16, lz = i / 384;
        int z2 = z2b + lz, y2 = y2b + ly, x2 = x2b + lx;
        float val = 0.f;
        if ((unsigned)z2 < 16u && (unsigned)y2 < 32u && (unsigned)x2 < 64u) {
            const float* b0 = &r1[((size_t)(2 * z2) * 64 + 2 * y2) * 128 + 2 * x2];
            float2 a  = *reinterpret_cast<const float2*>(b0);
            float2 bq = *reinterpret_cast<const float2*>(b0 + 128);
            float2 cq = *reinterpret_cast<const float2*>(b0 + 64 * 128);
            float2 dq = *reinterpret_cast<const float2*>(b0 + 64 * 128 + 128);
            val = 0.125f * (a.x + a.y + bq.x + bq.y + cq.x + cq.y + dq.x + dq.y);
        }
        R2[lz][ly][lx] = val;
    }
    __syncthreads();
    // Phase 2: r3 region (6*8*12 = 576); children at R2 local (2lz+dz, 2ly+dy, 2lx+dx)
    for (int i = tid; i < 576; i += 512) {
        int lx = i % 12, ly = (i / 12) % 8, lz = i / 96;
        int z3 = z3b + lz, y3 = y3b + ly, x3 = x3b + lx;
        float val = 0.f;
        if ((unsigned)z3 < 8u && (unsigned)y3 < 16u && (unsigned)x3 < 32u) {
            val = 0.125f * (R2[2*lz][2*ly][2*lx]     + R2[2*lz][2*ly][2*lx+1]
                          + R2[2*lz][2*ly+1][2*lx]   + R2[2*lz][2*ly+1][2*lx+1]
                          + R2[2*lz+1][2*ly][2*lx]   + R2[2*lz+1][2*ly][2*lx+1]
                          + R2[2*lz+1][2*ly+1][2*lx] + R2[2*lz+1][2*ly+1][2*lx+1]);
        }
        R3[lz][ly][lx] = val;
    }
    __syncthreads();
    // Phase 3: r4 region (3*4*6 = 72); children at R3 local (2lz+dz, ...)
    if (tid < 72) {
        int lx = tid % 6, ly = (tid / 6) % 4, lz = tid / 24;
        int z4 = z4b + lz, y4 = y4b + ly, x4 = x4b + lx;
        float val = 0.f;
        if ((unsigned)z4 < 4u && (unsigned)y4 < 8u && (unsigned)x4 < 16u) {
            val = 0.125f * (R3[2*lz][2*ly][2*lx]     + R3[2*lz][2*ly][2*lx+1]
                          + R3[2*lz][2*ly+1][2*lx]   + R3[2*lz][2*ly+1][2*lx+1]
                          + R3[2*lz+1][2*ly][2*lx]   + R3[2*lz+1][2*ly][2*lx+1]
                          + R3[2*lz+1][2*ly+1][2*lx] + R3[2*lz+1][2*ly+1][2*lx+1]);
        }
        R4[lz][ly][lx] = val;
    }
    __syncthreads();
    // write own r4 tile (z4=bz, y4 in [2by,2by+2), x4 in [4bx,4bx+4))
    if (tid < 8) {
        int tx4 = tid & 3, ty4 = tid >> 2;
        r4out[((bz * 8) + 2 * by + ty4) * 16 + 4 * bx + tx4] = R4[1][1 + ty4][1 + tx4];
    }
    // Phase 4: B tile (A = r4/diag prolonged; r3 from LDS)
    auto a4l = [&](int z3, int y3, int x3) -> float {
        if ((unsigned)z3 >= 8u || (unsigned)y3 >= 16u || (unsigned)x3 >= 32u) return 0.f;
        return R4[(z3 >> 1) - z4b][(y3 >> 1) - y4b][(x3 >> 1) - x4b] * IDIAG;
    };
    int B0z = 2 * bz - 1, B0y = 4 * by - 1, B0x = 8 * bx - 1;
    if (tid < 240) {
        int lx = tid % 10, ly = (tid / 10) % 6, lz = tid / 60;
        int z3 = B0z + lz, y3 = B0y + ly, x3 = B0x + lx;
        float val = 0.f;
        if ((unsigned)z3 < 8u && (unsigned)y3 < 16u && (unsigned)x3 < 32u) {
            float wcn = R4[(z3 >> 1) - z4b][(y3 >> 1) - y4b][(x3 >> 1) - x4b] * IDIAG;
            float lap = a4l(z3 - 1, y3, x3) + a4l(z3 + 1, y3, x3)
                      + a4l(z3, y3 - 1, x3) + a4l(z3, y3 + 1, x3)
                      + a4l(z3, y3, x3 - 1) + a4l(z3, y3, x3 + 1) - 6.f * wcn;
            val = wcn - lap * IDIAG + R3[z3 - z3b][y3 - y3b][x3 - x3b] * IDIAG;
        }
        Bl[lz][ly][lx] = val;
    }
    __syncthreads();
    // Phase 5: C tile+halo (r2 from LDS)
    int C0z = 4 * bz - 1, C0y = 8 * by - 1, C0x = 16 * bx - 1;
    auto pB = [&](int z2, int y2, int x2) -> float {
        if ((unsigned)z2 >= 16u || (unsigned)y2 >= 32u || (unsigned)x2 >= 64u) return 0.f;
        return Bl[(z2 >> 1) - B0z][(y2 >> 1) - B0y][(x2 >> 1) - B0x];
    };
    for (int i = tid; i < 1080; i += 512) {
        int lx = i % 18, ly = (i / 18) % 10, lz = i / 180;
        int z2 = C0z + lz, y2 = C0y + ly, x2 = C0x + lx;
        float val = 0.f;
        if ((unsigned)z2 < 16u && (unsigned)y2 < 32u && (unsigned)x2 < 64u) {
            float wB = Bl[(z2 >> 1) - B0z][(y2 >> 1) - B0y][(x2 >> 1) - B0x];
            float lap = pB(z2 - 1, y2, x2) + pB(z2 + 1, y2, x2)
                      + pB(z2, y2 - 1, x2) + pB(z2, y2 + 1, x2)
                      + pB(z2, y2, x2 - 1) + pB(z2, y2, x2 + 1) - 6.f * wB;
            val = wB - lap * IDIAG + R2[z2 - z2b][y2 - y2b][x2 - x2b] * IDIAG;
        }
        Cl[lz][ly][lx] = val;
    }
    __syncthreads();
    // Phase 6: D (level-1) from C + global r1
    auto pC = [&](int z1, int y1, int x1) -> float {
        if ((unsigned)z1 >= 32u || (unsigned)y1 >= 64u || (unsigned)x1 >= 128u) return 0.f;
        return Cl[(z1 >> 1) - C0z][(y1 >> 1) - C0y][(x1 >> 1) - C0x];
    };
    for (int i = tid; i < 4096; i += 512) {
        int lx = i & 31, ly = (i >> 5) & 15, lz = i >> 9;
        int z1 = bz * 8 + lz, y1 = by * 16 + ly, x1 = bx * 32 + lx;
        float wC = Cl[(z1 >> 1) - C0z][(y1 >> 1) - C0y][(x1 >> 1) - C0x];
        float lap = pC(z1 - 1, y1, x1) + pC(z1 + 1, y1, x1)
                  + pC(z1, y1 - 1, x1) + pC(z1, y1 + 1, x1)
                  + pC(z1, y1, x1 - 1) + pC(z1, y1, x1 + 1) - 6.f * wC;
        int idx = (z1 * 64 + y1) * 128 + x1;
        D[idx] = wC - lap * IDIAG + r1[idx] * IDIAG;
    }
}

// K5: iter0 p-update + iter1 residual (linearity) + fused restriction of r1res.
__global__ __launch_bounds__(512) void k_pup_resid_r(
    const float* __restrict__ pin, const float* __restrict__ D0,
    const float* __restrict__ r0, float* __restrict__ p1, float* __restrict__ r1res,
    float* __restrict__ r1) {
    __shared__ float lds[2][4][256];
    int tx = threadIdx.x, ty = threadIdx.y, tz = threadIdx.z;
    int y, z, ytile, ztile;
    decode_f2(blockIdx.x, y, z, ytile, ztile);
    int x0 = tx << 2, c = idx3(z, y, x0);
    int cz = z >> 1, cy = y >> 1, cx0 = tx << 1;

    const float* Drow = &D0[(cz * 64 + cy) * 128];
    float cr[4];
    cr[1] = Drow[cx0]; cr[2] = Drow[cx0 + 1];
    cr[0] = tx ? Drow[cx0 - 1] : cr[1];
    cr[3] = (tx < 63) ? Drow[cx0 + 2] : cr[2];
    int cym = y ? (y - 1) >> 1 : 0, cyp = (y < NY - 1) ? (y + 1) >> 1 : cy;
    int czm = z ? (z - 1) >> 1 : 0, czp = (z < NZ - 1) ? (z + 1) >> 1 : cz;
    float2 dym = *reinterpret_cast<const float2*>(&D0[(cz * 64 + cym) * 128 + cx0]);
    float2 dyp = *reinterpret_cast<const float2*>(&D0[(cz * 64 + cyp) * 128 + cx0]);
    float2 dzm = *reinterpret_cast<const float2*>(&D0[(czm * 64 + cy) * 128 + cx0]);
    float2 dzp = *reinterpret_cast<const float2*>(&D0[(czp * 64 + cy) * 128 + cx0]);

    F4 rc, rym, ryp, rzm, rzp, pin4;
    rc.v  = ld4(r0, z, y, x0);
    rym.v = ld4(r0, z, y > 0 ? y - 1 : 0, x0);
    ryp.v = ld4(r0, z, y < NY - 1 ? y + 1 : y, x0);
    rzm.v = ld4(r0, z > 0 ? z - 1 : 0, y, x0);
    rzp.v = ld4(r0, z < NZ - 1 ? z + 1 : z, y, x0);
    pin4.v = ld4(pin, z, y, x0);
    float rxmS = tx ? r0[c - 1] : rc.f[0];
    float rxpS = (tx < 63) ? r0[c + 4] : rc.f[3];

    F4 op1, ores;
    #pragma unroll
    for (int i = 0; i < 4; i++) {
        float Dc  = cr[1 + (i >> 1)];
        float Dxm = (i == 0) ? cr[0] : cr[1 + ((i - 1) >> 1)];
        float Dxp = (i == 3) ? cr[3] : cr[1 + ((i + 1) >> 1)];
        float Dym = (i < 2) ? dym.x : dym.y;
        float Dyp = (i < 2) ? dyp.x : dyp.y;
        float Dzm = (i < 2) ? dzm.x : dzm.y;
        float Dzp = (i < 2) ? dzp.x : dzp.y;
        float lapD = Dxm + Dxp + Dym + Dyp + Dzm + Dzp - 6.f * Dc;
        float rxm = i ? rc.f[i - 1] : rxmS, rxp = (i < 3) ? rc.f[i + 1] : rxpS;
        float lapR = rxm + rxp + rym.f[i] + ryp.f[i] + rzm.f[i] + rzp.f[i] - 6.f * rc.f[i];
        op1.f[i]  = pin4.f[i] - Dc + rc.f[i] * SIXTH;
        ores.f[i] = rc.f[i] - lapD + lapR * SIXTH;
    }
    st4(p1, c, op1); st4(r1res, c, ores);
    *reinterpret_cast<float4*>(&lds[tz][ty][x0]) = ores.v;
    __syncthreads();
    int tid = (tz * 4 + ty) * 64 + tx;
    if (tid < 256) {
        int y1loc = tid >> 7, x1 = tid & 127;
        int xf = x1 << 1, yf = y1loc << 1;
        float s = lds[0][yf][xf]     + lds[0][yf][xf + 1]
                + lds[0][yf + 1][xf] + lds[0][yf + 1][xf + 1]
                + lds[1][yf][xf]     + lds[1][yf][xf + 1]
                + lds[1][yf + 1][xf] + lds[1][yf + 1][xf + 1];
        int y1 = ytile * 2 + y1loc, z1 = ztile;
        r1[(z1 * 64 + y1) * 128 + x1] = 0.125f * s;
    }
}

// K6: fused final: p2 = p1 - prol(D1) + r1res/6 (recomputed at all 7 stencil
// points), then projection + solid_body.
__global__ __launch_bounds__(256) void k_pfin(
    const float* __restrict__ p1, const float* __restrict__ rr,
    const float* __restrict__ D1,
    float* __restrict__ uIO, float* __restrict__ vIO, float* __restrict__ wIO,
    const float* __restrict__ sg,
    float* __restrict__ pout, float* __restrict__ wmg) {
    int tx = threadIdx.x, y, z;
    decode_f(blockIdx.x, y, z);
    int x0 = tx << 2, c = idx3(z, y, x0);
    int cz = z >> 1, cy = y >> 1, cx0 = tx << 1;

    const float* Drow = &D1[(cz * 64 + cy) * 128];
    float cr[4];
    cr[1] = Drow[cx0]; cr[2] = Drow[cx0 + 1];
    cr[0] = tx ? Drow[cx0 - 1] : cr[1];
    cr[3] = (tx < 63) ? Drow[cx0 + 2] : cr[2];
    int cym = y ? (y - 1) >> 1 : 0, cyp = (y < NY - 1) ? (y + 1) >> 1 : cy;
    int czm = z ? (z - 1) >> 1 : 0, czp = (z < NZ - 1) ? (z + 1) >> 1 : cz;
    float2 dym = *reinterpret_cast<const float2*>(&D1[(cz * 64 + cym) * 128 + cx0]);
    float2 dyp = *reinterpret_cast<const float2*>(&D1[(cz * 64 + cyp) * 128 + cx0]);
    float2 dzm = *reinterpret_cast<const float2*>(&D1[(czm * 64 + cy) * 128 + cx0]);
    float2 dzp = *reinterpret_cast<const float2*>(&D1[(czp * 64 + cy) * 128 + cx0]);

    F4 pc, pym, pyp, pzm, pzp;
    pc.v  = ld4(p1, z, y, x0);
    pym.v = ld4(p1, z, y > 0 ? y - 1 : 0, x0);
    pyp.v = ld4(p1, z, y < NY - 1 ? y + 1 : y, x0);
    pzm.v = ld4(p1, z > 0 ? z - 1 : 0, y, x0);
    pzp.v = ld4(p1, z < NZ - 1 ? z + 1 : z, y, x0);
    F4 rc, rym, ryp, rzm, rzp;
    rc.v  = ld4(rr, z, y, x0);
    rym.v = ld4(rr, z, y > 0 ? y - 1 : 0, x0);
    ryp.v = ld4(rr, z, y < NY - 1 ? y + 1 : y, x0);
    rzm.v = ld4(rr, z > 0 ? z - 1 : 0, y, x0);
    rzp.v = ld4(rr, z < NZ - 1 ? z + 1 : z, y, x0);
    float pxmS = tx ? p1[c - 1] : pc.f[0];
    float pxpS = (tx < 63) ? p1[c + 4] : pc.f[3];
    float rxmS = tx ? rr[c - 1] : rc.f[0];
    float rxpS = (tx < 63) ? rr[c + 4] : rc.f[3];

    F4 sc; sc.v = ld4(sg, z, y, x0);
    F4 a, b, cc;
    a.v = ld4(uIO, z, y, x0); b.v = ld4(vIO, z, y, x0); cc.v = ld4(wIO, z, y, x0);

    F4 ou, ov, ow, op, owm;
    #pragma unroll
    for (int i = 0; i < 4; i++) {
        float Dc  = cr[1 + (i >> 1)];
        float Dxm = (i == 0) ? cr[0] : cr[1 + ((i - 1) >> 1)];
        float Dxp = (i == 3) ? cr[3] : cr[1 + ((i + 1) >> 1)];
        float Dym = (i < 2) ? dym.x : dym.y;
        float Dyp = (i < 2) ? dyp.x : dyp.y;
        float Dzm = (i < 2) ? dzm.x : dzm.y;
        float Dzp = (i < 2) ? dzp.x : dzp.y;
        float pxm = i ? pc.f[i - 1] : pxmS, pxp = (i < 3) ? pc.f[i + 1] : pxpS;
        float rxm = i ? rc.f[i - 1] : rxmS, rxp = (i < 3) ? rc.f[i + 1] : rxpS;

        float p2c  = pc.f[i]  - Dc  + rc.f[i]  * SIXTH;
        float p2xm = pxm      - Dxm + rxm      * SIXTH;
        float p2xp = pxp      - Dxp + rxp      * SIXTH;
        float p2ym = pym.f[i] - Dym + rym.f[i] * SIXTH;
        float p2yp = pyp.f[i] - Dyp + ryp.f[i] * SIXTH;
        float p2zm = pzm.f[i] - Dzm + rzm.f[i] * SIXTH;
        float p2zp = pzp.f[i] - Dzp + rzp.f[i] * SIXTH;

        float dpx = 0.5f * (p2xp - p2xm);
        float dpy = 0.5f * (p2yp - p2ym);
        float dpz = 0.5f * (p2zp - p2zm);
        float inv = frcp(1.f + DT * sc.f[i]);
        ou.f[i]  = (a.f[i]  - dpx * DT) * inv;
        ov.f[i]  = (b.f[i]  - dpy * DT) * inv;
        ow.f[i]  = (cc.f[i] - dpz * DT) * inv;
        op.f[i]  = p2c;
        owm.f[i] = Dc;
    }
    st4(uIO, c, ou); st4(vIO, c, ov); st4(wIO, c, ow);
    st4(pout, c, op); st4(wmg, c, owm);
}

extern "C" void kernel_launch(void* const* d_in, const int* in_sizes, int n_in,
                              void* d_out, int out_size, void* d_ws, size_t ws_size,
                              hipStream_t stream) {
    const float* in_u  = (const float*)d_in[0];
    const float* in_v  = (const float*)d_in[1];
    const float* in_w  = (const float*)d_in[2];
    const float* in_p  = (const float*)d_in[3];
    const float* in_sg = (const float*)d_in[4];

    float* out   = (float*)d_out;
    float* O_u   = out;                      // u2 -> u_out
    float* O_v   = out + (size_t)NTOT;       // v2 -> v_out
    float* O_w   = out + (size_t)2 * NTOT;   // w2 -> w_out
    float* O_p   = out + (size_t)3 * NTOT;   // p2 (written once, by k_pfin)
    float* O_wmg = out + (size_t)4 * NTOT;   // r0 -> wmg
    float* O_r   = out + (size_t)5 * NTOT;   // final coarsest residual (512)

    float* ws  = (float*)d_ws;
    float* B0  = ws;                          // bu -> p1
    float* B1  = ws + (size_t)NTOT;           // bv -> r1res
    float* B2  = ws + (size_t)2 * NTOT;       // bw
    float* r1  = ws + (size_t)3 * NTOT;       // 262144
    float* r4w = r1 + 262144;                 // 512 (iter0 r4, unused output)
    float* Dw  = r4w + 512;                   // 262144

    dim3 gF(2048);             dim3 bF(64, 4);
    dim3 gF2(1024);            dim3 bF2(64, 4, 2);
    dim3 gC(4, 4, 4);

    k_predict     <<<gF,  bF,  0, stream>>>(in_u, in_v, in_w, in_p, in_sg, B0, B1, B2);
    k_correct     <<<gF,  bF,  0, stream>>>(in_u, in_v, in_w, in_sg, B0, B1, B2, in_p,
                                            O_u, O_v, O_w);
    k_divresid_r  <<<gF2, bF2, 0, stream>>>(O_u, O_v, O_w, in_p, O_wmg /*r0*/, r1);

    // --- MG iteration 0 ---
    k_mgall       <<<gC, dim3(512), 0, stream>>>(r1, r4w, Dw);
    k_pup_resid_r <<<gF2, bF2, 0, stream>>>(in_p, Dw, O_wmg, B0 /*p1*/, B1 /*r1res*/, r1);

    // --- MG iteration 1 ---
    k_mgall       <<<gC, dim3(512), 0, stream>>>(r1, O_r, Dw);

    // fused p-update + projection + solid_body
    k_pfin        <<<gF, bF, 0, stream>>>(B0 /*p1*/, B1 /*r1res*/, Dw,
                                          O_u, O_v, O_w, in_sg, O_p, O_wmg);
}

// Round 13
// 89.341 us; speedup vs baseline: 1.0560x; 1.0560x over previous
//
#include <hip/hip_runtime.h>

// ---------------------------------------------------------------------------
// AI4Urban one-timestep NS solver on 64x128x256, f32.  Round 13 = R11 verbatim
// (champion, 88.9us).  R12's barrier-free mg fusion regressed (94.3) and is
// reverted: the two small coarse kernels are near-optimal; launch gaps ~1-2us.
//  9 dispatches: predict, correct, divresid+restrict, [down, upf, pup+resid+
//  restrict], [down, upf], pfin(p-update+projection).
// ---------------------------------------------------------------------------

constexpr int NZ = 64, NY = 128, NX = 256;
constexpr int NTOT = NZ * NY * NX;
constexpr float DT  = 0.01f;
constexpr float RDT = 100.0f;          // 1/DT
constexpr float RE  = 0.001f;
constexpr float UBC = -1.0f;
constexpr float SIXTH = 1.0f / 6.0f;
constexpr float IDIAG = -1.0f / 6.0f;  // 1/DIAG, DIAG=-6

__device__ __forceinline__ float frcp(float x) { return __builtin_amdgcn_rcpf(x); }

__device__ __forceinline__ int idx3(int z, int y, int x) {
    return (z * NY + y) * NX + x;
}

union F4 { float4 v; float f[4]; };

__device__ __forceinline__ float4 ld4(const float* __restrict__ f, int z, int y, int x0) {
    return *reinterpret_cast<const float4*>(&f[idx3(z, y, x0)]);
}
__device__ __forceinline__ void st4(float* __restrict__ f, int c, const F4& a) {
    *reinterpret_cast<float4*>(&f[c]) = a.v;
}
__device__ __forceinline__ float4 ldsrow(const float* r, int x0) {
    return *reinterpret_cast<const float4*>(&r[x0]);
}

__device__ __forceinline__ void zero4(float o[4]) {
    #pragma unroll
    for (int i = 0; i < 4; i++) o[i] = 0.f;
}

__device__ __forceinline__ void row0(const float* __restrict__ f, int z, int y, int x0,
                                     bool ok, float o[4]) {
    if (ok) { F4 a; a.v = ld4(f, z, y, x0);
        #pragma unroll
        for (int i = 0; i < 4; i++) o[i] = a.f[i];
    } else {
        zero4(o);
    }
}
__device__ __forceinline__ void row3s(const float* __restrict__ u, const float* __restrict__ v,
                                      const float* __restrict__ w, const float* __restrict__ sg,
                                      int z, int y, int x0, bool ok,
                                      float uo[4], float vo[4], float wo[4]) {
    if (ok) {
        F4 a, b, c, s;
        a.v = ld4(u, z, y, x0); b.v = ld4(v, z, y, x0);
        c.v = ld4(w, z, y, x0); s.v = ld4(sg, z, y, x0);
        #pragma unroll
        for (int i = 0; i < 4; i++) {
            float iv = frcp(1.f + DT * s.f[i]);
            uo[i] = a.f[i] * iv; vo[i] = b.f[i] * iv; wo[i] = c.f[i] * iv;
        }
    } else {
        zero4(uo); zero4(vo); zero4(wo);
    }
}

// XCD z-slab swizzle decode: 2048 blocks, block (64,4).
__device__ __forceinline__ void decode_f(int d, int& y, int& z) {
    int k = d & 7, j = d >> 3;
    z = 8 * k + (j >> 5);
    y = (j & 31) * 4 + threadIdx.y;
}
// 1024 blocks, block (64,4,2): XCD k owns ztile in [4k,4k+4).
__device__ __forceinline__ void decode_f2(int d, int& y, int& z, int& ytile, int& ztile) {
    int k = d & 7, j = d >> 3;
    ztile = 4 * k + (j >> 5);
    ytile = j & 31;
    z = ztile * 2 + threadIdx.z;
    y = ytile * 4 + threadIdx.y;
}

// K1: predictor, solid_body fused; LDS row-sharing across the 4-y block
__global__ __launch_bounds__(256) void k_predict(
    const float* __restrict__ u, const float* __restrict__ v, const float* __restrict__ w,
    const float* __restrict__ p, const float* __restrict__ sg,
    float* __restrict__ bu, float* __restrict__ bv, float* __restrict__ bw) {
    __shared__ __align__(16) float su[6][256], sv[6][256], sw[6][256], sp[6][256];
    int tx = threadIdx.x, ty = threadIdx.y, y, z;
    decode_f(blockIdx.x, y, z);
    int x0 = tx << 2, c = idx3(z, y, x0);

    F4 sc; sc.v = ld4(sg, z, y, x0);
    F4 u4, v4, w4; u4.v = ld4(u, z, y, x0); v4.v = ld4(v, z, y, x0); w4.v = ld4(w, z, y, x0);
    F4 pc; pc.v = ld4(p, z, y, x0);
    float inv[4], uc[4], vc[4], wc[4];
    #pragma unroll
    for (int i = 0; i < 4; i++) {
        inv[i] = frcp(1.f + DT * sc.f[i]);
        uc[i] = u4.f[i] * inv[i]; vc[i] = v4.f[i] * inv[i]; wc[i] = w4.f[i] * inv[i];
        su[ty + 1][x0 + i] = uc[i]; sv[ty + 1][x0 + i] = vc[i];
        sw[ty + 1][x0 + i] = wc[i]; sp[ty + 1][x0 + i] = pc.f[i];
    }
    if (ty == 0) {
        int ym = y - 1;
        if (ym >= 0) {
            F4 a, b, c2, s;
            a.v = ld4(u, z, ym, x0); b.v = ld4(v, z, ym, x0);
            c2.v = ld4(w, z, ym, x0); s.v = ld4(sg, z, ym, x0);
            #pragma unroll
            for (int i = 0; i < 4; i++) {
                float iv = frcp(1.f + DT * s.f[i]);
                su[0][x0 + i] = a.f[i] * iv; sv[0][x0 + i] = b.f[i] * iv;
                sw[0][x0 + i] = c2.f[i] * iv;
            }
        } else {
            #pragma unroll
            for (int i = 0; i < 4; i++) { su[0][x0+i] = 0.f; sv[0][x0+i] = 0.f; sw[0][x0+i] = 0.f; }
        }
        F4 pp; pp.v = ld4(p, z, ym >= 0 ? ym : 0, x0);
        #pragma unroll
        for (int i = 0; i < 4; i++) sp[0][x0 + i] = pp.f[i];
    } else if (ty == 3) {
        int yp = y + 1;
        if (yp < NY) {
            F4 a, b, c2, s;
            a.v = ld4(u, z, yp, x0); b.v = ld4(v, z, yp, x0);
            c2.v = ld4(w, z, yp, x0); s.v = ld4(sg, z, yp, x0);
            #pragma unroll
            for (int i = 0; i < 4; i++) {
                float iv = frcp(1.f + DT * s.f[i]);
                su[5][x0 + i] = a.f[i] * iv; sv[5][x0 + i] = b.f[i] * iv;
                sw[5][x0 + i] = c2.f[i] * iv;
            }
        } else {
            #pragma unroll
            for (int i = 0; i < 4; i++) { su[5][x0+i] = 0.f; sv[5][x0+i] = 0.f; sw[5][x0+i] = 0.f; }
        }
        F4 pp; pp.v = ld4(p, z, yp < NY ? yp : NY - 1, x0);
        #pragma unroll
        for (int i = 0; i < 4; i++) sp[5][x0 + i] = pp.f[i];
    }
    __syncthreads();

    F4 Uym, Uyp, Vym, Vyp, Wym, Wyp, Pym, Pyp;
    Uym.v = ldsrow(su[ty], x0);     Uyp.v = ldsrow(su[ty + 2], x0);
    Vym.v = ldsrow(sv[ty], x0);     Vyp.v = ldsrow(sv[ty + 2], x0);
    Wym.v = ldsrow(sw[ty], x0);     Wyp.v = ldsrow(sw[ty + 2], x0);
    Pym.v = ldsrow(sp[ty], x0);     Pyp.v = ldsrow(sp[ty + 2], x0);

    float uzm[4], vzm[4], wzm[4], uzp[4], vzp[4], wzp[4];
    row3s(u, v, w, sg, z - 1, y, x0, z > 0,      uzm, vzm, wzm);
    row3s(u, v, w, sg, z + 1, y, x0, z < NZ - 1, uzp, vzp, wzp);
    F4 pzm, pzp;
    pzm.v = ld4(p, z > 0 ? z - 1 : 0, y, x0);
    pzp.v = ld4(p, z < NZ - 1 ? z + 1 : z, y, x0);

    float uxmS = tx ? su[ty + 1][x0 - 1] : UBC;
    float vxmS = tx ? sv[ty + 1][x0 - 1] : 0.f;
    float wxmS = tx ? sw[ty + 1][x0 - 1] : 0.f;
    float uxpS = (tx < 63) ? su[ty + 1][x0 + 4] : 0.f;
    float vxpS = (tx < 63) ? sv[ty + 1][x0 + 4] : 0.f;
    float wxpS = (tx < 63) ? sw[ty + 1][x0 + 4] : 0.f;
    float pxmS = tx ? sp[ty + 1][x0 - 1] : pc.f[0];
    float pxpS = (tx < 63) ? sp[ty + 1][x0 + 4] : pc.f[3];

    F4 obu, obv, obw;
    #pragma unroll
    for (int i = 0; i < 4; i++) {
        float uxm = i ? uc[i - 1] : uxmS, uxp = (i < 3) ? uc[i + 1] : uxpS;
        float vxm = i ? vc[i - 1] : vxmS, vxp = (i < 3) ? vc[i + 1] : vxpS;
        float wxm = i ? wc[i - 1] : wxmS, wxp = (i < 3) ? wc[i + 1] : wxpS;
        float pxm = i ? pc.f[i - 1] : pxmS, pxp = (i < 3) ? pc.f[i + 1] : pxpS;
        float dpx = 0.5f * (pxp - pxm);
        float dpy = 0.5f * (Pyp.f[i] - Pym.f[i]);
        float dpz = 0.5f * (pzp.f[i] - pzm.f[i]);
        float lap_u = uxm + uxp + Uym.f[i] + Uyp.f[i] + uzm[i] + uzp[i] - 6.f * uc[i];
        float lap_v = vxm + vxp + Vym.f[i] + Vyp.f[i] + vzm[i] + vzp[i] - 6.f * vc[i];
        float lap_w = wxm + wxp + Wym.f[i] + Wyp.f[i] + wzm[i] + wzp[i] - 6.f * wc[i];
        float bun = uc[i] + 0.5f * (RE * lap_u * DT
                    - uc[i] * (0.5f * (uxp - uxm)) * DT
                    - vc[i] * (0.5f * (Uyp.f[i] - Uym.f[i])) * DT
                    - wc[i] * (0.5f * (uzp[i] - uzm[i])) * DT) - dpx * DT;
        float bvn = vc[i] + 0.5f * (RE * lap_v * DT
                    - uc[i] * (0.5f * (vxp - vxm)) * DT
                    - vc[i] * (0.5f * (Vyp.f[i] - Vym.f[i])) * DT
                    - wc[i] * (0.5f * (vzp[i] - vzm[i])) * DT) - dpy * DT;
        float bwn = wc[i] + 0.5f * (RE * lap_w * DT
                    - uc[i] * (0.5f * (wxp - wxm)) * DT
                    - vc[i] * (0.5f * (Wyp.f[i] - Wym.f[i])) * DT
                    - wc[i] * (0.5f * (wzp[i] - wzm[i])) * DT) - dpz * DT;
        obu.f[i] = bun * inv[i];
        obv.f[i] = bvn * inv[i];
        obw.f[i] = bwn * inv[i];
    }
    st4(bu, c, obu); st4(bv, c, obv); st4(bw, c, obw);
}

// K2: corrector; LDS row-sharing of bu/bv/bw and p
__global__ __launch_bounds__(256) void k_correct(
    const float* __restrict__ u, const float* __restrict__ v, const float* __restrict__ w,
    const float* __restrict__ sg,
    const float* __restrict__ bu, const float* __restrict__ bv, const float* __restrict__ bw,
    const float* __restrict__ p,
    float* __restrict__ u2, float* __restrict__ v2, float* __restrict__ w2) {
    __shared__ __align__(16) float su[6][256], sv[6][256], sw[6][256], sp[6][256];
    int tx = threadIdx.x, ty = threadIdx.y, y, z;
    decode_f(blockIdx.x, y, z);
    int x0 = tx << 2, c = idx3(z, y, x0);

    F4 sc; sc.v = ld4(sg, z, y, x0);
    F4 u4, v4, w4; u4.v = ld4(u, z, y, x0); v4.v = ld4(v, z, y, x0); w4.v = ld4(w, z, y, x0);
    F4 buc, bvc, bwc; buc.v = ld4(bu, z, y, x0); bvc.v = ld4(bv, z, y, x0); bwc.v = ld4(bw, z, y, x0);
    F4 pc; pc.v = ld4(p, z, y, x0);
    #pragma unroll
    for (int i = 0; i < 4; i++) {
        su[ty + 1][x0 + i] = buc.f[i]; sv[ty + 1][x0 + i] = bvc.f[i];
        sw[ty + 1][x0 + i] = bwc.f[i]; sp[ty + 1][x0 + i] = pc.f[i];
    }
    if (ty == 0) {
        int ym = y - 1;
        if (ym >= 0) {
            F4 a, b, c2;
            a.v = ld4(bu, z, ym, x0); b.v = ld4(bv, z, ym, x0); c2.v = ld4(bw, z, ym, x0);
            #pragma unroll
            for (int i = 0; i < 4; i++) { su[0][x0+i] = a.f[i]; sv[0][x0+i] = b.f[i]; sw[0][x0+i] = c2.f[i]; }
        } else {
            #pragma unroll
            for (int i = 0; i < 4; i++) { su[0][x0+i] = 0.f; sv[0][x0+i] = 0.f; sw[0][x0+i] = 0.f; }
        }
        F4 pp; pp.v = ld4(p, z, ym >= 0 ? ym : 0, x0);
        #pragma unroll
        for (int i = 0; i < 4; i++) sp[0][x0 + i] = pp.f[i];
    } else if (ty == 3) {
        int yp = y + 1;
        if (yp < NY) {
            F4 a, b, c2;
            a.v = ld4(bu, z, yp, x0); b.v = ld4(bv, z, yp, x0); c2.v = ld4(bw, z, yp, x0);
            #pragma unroll
            for (int i = 0; i < 4; i++) { su[5][x0+i] = a.f[i]; sv[5][x0+i] = b.f[i]; sw[5][x0+i] = c2.f[i]; }
        } else {
            #pragma unroll
            for (int i = 0; i < 4; i++) { su[5][x0+i] = 0.f; sv[5][x0+i] = 0.f; sw[5][x0+i] = 0.f; }
        }
        F4 pp; pp.v = ld4(p, z, yp < NY ? yp : NY - 1, x0);
        #pragma unroll
        for (int i = 0; i < 4; i++) sp[5][x0 + i] = pp.f[i];
    }
    __syncthreads();

    F4 Uym, Uyp, Vym, Vyp, Wym, Wyp, Pym, Pyp;
    Uym.v = ldsrow(su[ty], x0);     Uyp.v = ldsrow(su[ty + 2], x0);
    Vym.v = ldsrow(sv[ty], x0);     Vyp.v = ldsrow(sv[ty + 2], x0);
    Wym.v = ldsrow(sw[ty], x0);     Wyp.v = ldsrow(sw[ty + 2], x0);
    Pym.v = ldsrow(sp[ty], x0);     Pyp.v = ldsrow(sp[ty + 2], x0);

    float uzm[4], vzm[4], wzm[4], uzp[4], vzp[4], wzp[4];
    row0(bu, z - 1, y, x0, z > 0, uzm);      row0(bv, z - 1, y, x0, z > 0, vzm);
    row0(bw, z - 1, y, x0, z > 0, wzm);
    row0(bu, z + 1, y, x0, z < NZ - 1, uzp); row0(bv, z + 1, y, x0, z < NZ - 1, vzp);
    row0(bw, z + 1, y, x0, z < NZ - 1, wzp);
    F4 pzm, pzp;
    pzm.v = ld4(p, z > 0 ? z - 1 : 0, y, x0);
    pzp.v = ld4(p, z < NZ - 1 ? z + 1 : z, y, x0);

    float uxmS = tx ? su[ty + 1][x0 - 1] : UBC;
    float vxmS = tx ? sv[ty + 1][x0 - 1] : 0.f;
    float wxmS = tx ? sw[ty + 1][x0 - 1] : 0.f;
    float uxpS = (tx < 63) ? su[ty + 1][x0 + 4] : 0.f;
    float vxpS = (tx < 63) ? sv[ty + 1][x0 + 4] : 0.f;
    float wxpS = (tx < 63) ? sw[ty + 1][x0 + 4] : 0.f;
    float pxmS = tx ? sp[ty + 1][x0 - 1] : pc.f[0];
    float pxpS = (tx < 63) ? sp[ty + 1][x0 + 4] : pc.f[3];

    F4 ou, ov, ow;
    #pragma unroll
    for (int i = 0; i < 4; i++) {
        float inv = frcp(1.f + DT * sc.f[i]);
        float u1c = u4.f[i] * inv, v1c = v4.f[i] * inv, w1c = w4.f[i] * inv;
        float uxm = i ? buc.f[i - 1] : uxmS, uxp = (i < 3) ? buc.f[i + 1] : uxpS;
        float vxm = i ? bvc.f[i - 1] : vxmS, vxp = (i < 3) ? bvc.f[i + 1] : vxpS;
        float wxm = i ? bwc.f[i - 1] : wxmS, wxp = (i < 3) ? bwc.f[i + 1] : wxpS;
        float pxm = i ? pc.f[i - 1] : pxmS, pxp = (i < 3) ? pc.f[i + 1] : pxpS;
        float dpx = 0.5f * (pxp - pxm);
        float dpy = 0.5f * (Pyp.f[i] - Pym.f[i]);
        float dpz = 0.5f * (pzp.f[i] - pzm.f[i]);
        float lap_u = uxm + uxp + Uym.f[i] + Uyp.f[i] + uzm[i] + uzp[i] - 6.f * buc.f[i];
        float lap_v = vxm + vxp + Vym.f[i] + Vyp.f[i] + vzm[i] + vzp[i] - 6.f * bvc.f[i];
        float lap_w = wxm + wxp + Wym.f[i] + Wyp.f[i] + wzm[i] + wzp[i] - 6.f * bwc.f[i];
        float un = u1c + RE * lap_u * DT
                   - buc.f[i] * (0.5f * (uxp - uxm)) * DT
                   - bvc.f[i] * (0.5f * (Uyp.f[i] - Uym.f[i])) * DT
                   - bwc.f[i] * (0.5f * (uzp[i] - uzm[i])) * DT - dpx * DT;
        float vn = v1c + RE * lap_v * DT
                   - buc.f[i] * (0.5f * (vxp - vxm)) * DT
                   - bvc.f[i] * (0.5f * (Vyp.f[i] - Vym.f[i])) * DT
                   - bwc.f[i] * (0.5f * (vzp[i] - vzm[i])) * DT - dpy * DT;
        float wn = w1c + RE * lap_w * DT
                   - buc.f[i] * (0.5f * (wxp - wxm)) * DT
                   - bvc.f[i] * (0.5f * (Wyp.f[i] - Wym.f[i])) * DT
                   - bwc.f[i] * (0.5f * (wzp[i] - wzm[i])) * DT - dpz * DT;
        ou.f[i] = un * inv; ov.f[i] = vn * inv; ow.f[i] = wn * inv;
    }
    st4(u2, c, ou); st4(v2, c, ov); st4(w2, c, ow);
}

// K3: r0 = lap_ep(p) - b (b inline), plus fused level-0->1 restriction of r0.
__global__ __launch_bounds__(512) void k_divresid_r(
    const float* __restrict__ u2, const float* __restrict__ v2, const float* __restrict__ w2,
    const float* __restrict__ p, float* __restrict__ r0, float* __restrict__ r1) {
    __shared__ float lds[2][4][256];
    int tx = threadIdx.x, ty = threadIdx.y, tz = threadIdx.z;
    int y, z, ytile, ztile;
    decode_f2(blockIdx.x, y, z, ytile, ztile);
    int x0 = tx << 2, c = idx3(z, y, x0);

    F4 uc; uc.v = ld4(u2, z, y, x0);
    float uxmS = tx ? u2[c - 1] : UBC, uxpS = (tx < 63) ? u2[c + 4] : 0.f;
    float vym[4], vyp[4], wzm[4], wzp[4];
    row0(v2, z, y - 1, x0, y > 0, vym);
    row0(v2, z, y + 1, x0, y < NY - 1, vyp);
    row0(w2, z - 1, y, x0, z > 0, wzm);
    row0(w2, z + 1, y, x0, z < NZ - 1, wzp);

    F4 pc, pym, pyp, pzm, pzp;
    pc.v  = ld4(p, z, y, x0);
    pym.v = ld4(p, z, y > 0 ? y - 1 : 0, x0);
    pyp.v = ld4(p, z, y < NY - 1 ? y + 1 : y, x0);
    pzm.v = ld4(p, z > 0 ? z - 1 : 0, y, x0);
    pzp.v = ld4(p, z < NZ - 1 ? z + 1 : z, y, x0);
    float pxmS = tx ? p[c - 1] : pc.f[0];
    float pxpS = (tx < 63) ? p[c + 4] : pc.f[3];

    F4 o;
    #pragma unroll
    for (int i = 0; i < 4; i++) {
        float uxm = i ? uc.f[i - 1] : uxmS, uxp = (i < 3) ? uc.f[i + 1] : uxpS;
        float bval = -(0.5f * (uxp - uxm) + 0.5f * (vyp[i] - vym[i])
                       + 0.5f * (wzp[i] - wzm[i])) * RDT;
        float pxm = i ? pc.f[i - 1] : pxmS, pxp = (i < 3) ? pc.f[i + 1] : pxpS;
        float lap = pxm + pxp + pym.f[i] + pyp.f[i] + pzm.f[i] + pzp.f[i] - 6.f * pc.f[i];
        o.f[i] = lap - bval;
    }
    st4(r0, c, o);
    *reinterpret_cast<float4*>(&lds[tz][ty][x0]) = o.v;
    __syncthreads();
    int tid = (tz * 4 + ty) * 64 + tx;
    if (tid < 256) {
        int y1loc = tid >> 7, x1 = tid & 127;
        int xf = x1 << 1, yf = y1loc << 1;
        float s = lds[0][yf][xf]     + lds[0][yf][xf + 1]
                + lds[0][yf + 1][xf] + lds[0][yf + 1][xf + 1]
                + lds[1][yf][xf]     + lds[1][yf][xf + 1]
                + lds[1][yf + 1][xf] + lds[1][yf + 1][xf + 1];
        int y1 = ytile * 2 + y1loc, z1 = ztile;
        r1[(z1 * 64 + y1) * 128 + x1] = 0.125f * s;
    }
}

// K4: coarse down-chain r1(32,64,128) -> r2, r3, r4.  grid(4,4,4), block 512
__global__ __launch_bounds__(512) void k_down(const float* __restrict__ r1,
    float* __restrict__ r2, float* __restrict__ r3, float* __restrict__ r4) {
    __shared__ float l2[4][8][16];
    __shared__ float l3[2][4][8];
    int tid = threadIdx.x;
    int bx = blockIdx.x, by = blockIdx.y, bz = blockIdx.z;
    {
        int tx2 = tid & 15, ty2 = (tid >> 4) & 7, tz2 = tid >> 7;
        int x2 = bx * 16 + tx2, y2 = by * 8 + ty2, z2 = bz * 4 + tz2;
        const float* b0 = &r1[((size_t)(2 * z2) * 64 + 2 * y2) * 128 + 2 * x2];
        float2 a  = *reinterpret_cast<const float2*>(b0);
        float2 bq = *reinterpret_cast<const float2*>(b0 + 128);
        float2 cq = *reinterpret_cast<const float2*>(b0 + 64 * 128);
        float2 dq = *reinterpret_cast<const float2*>(b0 + 64 * 128 + 128);
        float val = 0.125f * (a.x + a.y + bq.x + bq.y + cq.x + cq.y + dq.x + dq.y);
        l2[tz2][ty2][tx2] = val;
        r2[((z2 * 32) + y2) * 64 + x2] = val;
    }
    __syncthreads();
    if (tid < 64) {
        int tx3 = tid & 7, ty3 = (tid >> 3) & 3, tz3 = tid >> 5;
        float s = l2[2*tz3][2*ty3][2*tx3]     + l2[2*tz3][2*ty3][2*tx3+1]
                + l2[2*tz3][2*ty3+1][2*tx3]   + l2[2*tz3][2*ty3+1][2*tx3+1]
                + l2[2*tz3+1][2*ty3][2*tx3]   + l2[2*tz3+1][2*ty3][2*tx3+1]
                + l2[2*tz3+1][2*ty3+1][2*tx3] + l2[2*tz3+1][2*ty3+1][2*tx3+1];
        float val = 0.125f * s;
        l3[tz3][ty3][tx3] = val;
        int x3 = bx * 8 + tx3, y3 = by * 4 + ty3, z3 = bz * 2 + tz3;
        r3[((z3 * 16) + y3) * 32 + x3] = val;
    }
    __syncthreads();
    if (tid < 8) {
        int tx4 = tid & 3, ty4 = tid >> 2;
        float s = l3[0][2*ty4][2*tx4]   + l3[0][2*ty4][2*tx4+1]
                + l3[0][2*ty4+1][2*tx4] + l3[0][2*ty4+1][2*tx4+1]
                + l3[1][2*ty4][2*tx4]   + l3[1][2*ty4][2*tx4+1]
                + l3[1][2*ty4+1][2*tx4] + l3[1][2*ty4+1][2*tx4+1];
        int x4 = bx * 4 + tx4, y4 = by * 2 + ty4, z4 = bz;
        r4[((z4 * 8) + y4) * 16 + x4] = 0.125f * s;
    }
}

__device__ __forceinline__ float a4p(const float* __restrict__ r4, int z3, int y3, int x3) {
    if ((unsigned)z3 >= 8u || (unsigned)y3 >= 16u || (unsigned)x3 >= 32u) return 0.f;
    return r4[(((z3 >> 1) * 8) + (y3 >> 1)) * 16 + (x3 >> 1)] * IDIAG;
}

// K5: fused coarse up-chain: A=r4/diag -> B(LDS) -> C+halo(LDS) -> D(level-1 out)
__global__ __launch_bounds__(512) void k_upf(const float* __restrict__ r4,
    const float* __restrict__ r3, const float* __restrict__ r2,
    const float* __restrict__ r1, float* __restrict__ D) {
    __shared__ float Bl[4][6][10];
    __shared__ float Cl[6][10][18];
    int tid = threadIdx.x;
    int bx = blockIdx.x, by = blockIdx.y, bz = blockIdx.z;
    int B0z = bz * 2 - 1, B0y = by * 4 - 1, B0x = bx * 8 - 1;
    if (tid < 240) {
        int lx = tid % 10, ly = (tid / 10) % 6, lz = tid / 60;
        int z3 = B0z + lz, y3 = B0y + ly, x3 = B0x + lx;
        float val = 0.f;
        if ((unsigned)z3 < 8u && (unsigned)y3 < 16u && (unsigned)x3 < 32u) {
            float wcn = r4[(((z3 >> 1) * 8) + (y3 >> 1)) * 16 + (x3 >> 1)] * IDIAG;
            float lap = a4p(r4, z3 - 1, y3, x3) + a4p(r4, z3 + 1, y3, x3)
                      + a4p(r4, z3, y3 - 1, x3) + a4p(r4, z3, y3 + 1, x3)
                      + a4p(r4, z3, y3, x3 - 1) + a4p(r4, z3, y3, x3 + 1) - 6.f * wcn;
            val = wcn - lap * IDIAG + r3[((z3 * 16) + y3) * 32 + x3] * IDIAG;
        }
        Bl[lz][ly][lx] = val;
    }
    __syncthreads();
    int C0z = bz * 4 - 1, C0y = by * 8 - 1, C0x = bx * 16 - 1;
    auto pB = [&](int z2, int y2, int x2) -> float {
        if ((unsigned)z2 >= 16u || (unsigned)y2 >= 32u || (unsigned)x2 >= 64u) return 0.f;
        return Bl[(z2 >> 1) - B0z][(y2 >> 1) - B0y][(x2 >> 1) - B0x];
    };
    for (int i = tid; i < 1080; i += 512) {
        int lx = i % 18, ly = (i / 18) % 10, lz = i / 180;
        int z2 = C0z + lz, y2 = C0y + ly, x2 = C0x + lx;
        float val = 0.f;
        if ((unsigned)z2 < 16u && (unsigned)y2 < 32u && (unsigned)x2 < 64u) {
            float wB = Bl[(z2 >> 1) - B0z][(y2 >> 1) - B0y][(x2 >> 1) - B0x];
            float lap = pB(z2 - 1, y2, x2) + pB(z2 + 1, y2, x2)
                      + pB(z2, y2 - 1, x2) + pB(z2, y2 + 1, x2)
                      + pB(z2, y2, x2 - 1) + pB(z2, y2, x2 + 1) - 6.f * wB;
            val = wB - lap * IDIAG + r2[((z2 * 32) + y2) * 64 + x2] * IDIAG;
        }
        Cl[lz][ly][lx] = val;
    }
    __syncthreads();
    auto pC = [&](int z1, int y1, int x1) -> float {
        if ((unsigned)z1 >= 32u || (unsigned)y1 >= 64u || (unsigned)x1 >= 128u) return 0.f;
        return Cl[(z1 >> 1) - C0z][(y1 >> 1) - C0y][(x1 >> 1) - C0x];
    };
    for (int i = tid; i < 4096; i += 512) {
        int lx = i & 31, ly = (i >> 5) & 15, lz = i >> 9;
        int z1 = bz * 8 + lz, y1 = by * 16 + ly, x1 = bx * 32 + lx;
        float wC = Cl[(z1 >> 1) - C0z][(y1 >> 1) - C0y][(x1 >> 1) - C0x];
        float lap = pC(z1 - 1, y1, x1) + pC(z1 + 1, y1, x1)
                  + pC(z1, y1 - 1, x1) + pC(z1, y1 + 1, x1)
                  + pC(z1, y1, x1 - 1) + pC(z1, y1, x1 + 1) - 6.f * wC;
        int idx = (z1 * 64 + y1) * 128 + x1;
        D[idx] = wC - lap * IDIAG + r1[idx] * IDIAG;
    }
}

// K6: iter0 p-update + iter1 residual (linearity) + fused restriction of r1res.
__global__ __launch_bounds__(512) void k_pup_resid_r(
    const float* __restrict__ pin, const float* __restrict__ D0,
    const float* __restrict__ r0, float* __restrict__ p1, float* __restrict__ r1res,
    float* __restrict__ r1) {
    __shared__ float lds[2][4][256];
    int tx = threadIdx.x, ty = threadIdx.y, tz = threadIdx.z;
    int y, z, ytile, ztile;
    decode_f2(blockIdx.x, y, z, ytile, ztile);
    int x0 = tx << 2, c = idx3(z, y, x0);
    int cz = z >> 1, cy = y >> 1, cx0 = tx << 1;

    const float* Drow = &D0[(cz * 64 + cy) * 128];
    float cr[4];
    cr[1] = Drow[cx0]; cr[2] = Drow[cx0 + 1];
    cr[0] = tx ? Drow[cx0 - 1] : cr[1];
    cr[3] = (tx < 63) ? Drow[cx0 + 2] : cr[2];
    int cym = y ? (y - 1) >> 1 : 0, cyp = (y < NY - 1) ? (y + 1) >> 1 : cy;
    int czm = z ? (z - 1) >> 1 : 0, czp = (z < NZ - 1) ? (z + 1) >> 1 : cz;
    float2 dym = *reinterpret_cast<const float2*>(&D0[(cz * 64 + cym) * 128 + cx0]);
    float2 dyp = *reinterpret_cast<const float2*>(&D0[(cz * 64 + cyp) * 128 + cx0]);
    float2 dzm = *reinterpret_cast<const float2*>(&D0[(czm * 64 + cy) * 128 + cx0]);
    float2 dzp = *reinterpret_cast<const float2*>(&D0[(czp * 64 + cy) * 128 + cx0]);

    F4 rc, rym, ryp, rzm, rzp, pin4;
    rc.v  = ld4(r0, z, y, x0);
    rym.v = ld4(r0, z, y > 0 ? y - 1 : 0, x0);
    ryp.v = ld4(r0, z, y < NY - 1 ? y + 1 : y, x0);
    rzm.v = ld4(r0, z > 0 ? z - 1 : 0, y, x0);
    rzp.v = ld4(r0, z < NZ - 1 ? z + 1 : z, y, x0);
    pin4.v = ld4(pin, z, y, x0);
    float rxmS = tx ? r0[c - 1] : rc.f[0];
    float rxpS = (tx < 63) ? r0[c + 4] : rc.f[3];

    F4 op1, ores;
    #pragma unroll
    for (int i = 0; i < 4; i++) {
        float Dc  = cr[1 + (i >> 1)];
        float Dxm = (i == 0) ? cr[0] : cr[1 + ((i - 1) >> 1)];
        float Dxp = (i == 3) ? cr[3] : cr[1 + ((i + 1) >> 1)];
        float Dym = (i < 2) ? dym.x : dym.y;
        float Dyp = (i < 2) ? dyp.x : dyp.y;
        float Dzm = (i < 2) ? dzm.x : dzm.y;
        float Dzp = (i < 2) ? dzp.x : dzp.y;
        float lapD = Dxm + Dxp + Dym + Dyp + Dzm + Dzp - 6.f * Dc;
        float rxm = i ? rc.f[i - 1] : rxmS, rxp = (i < 3) ? rc.f[i + 1] : rxpS;
        float lapR = rxm + rxp + rym.f[i] + ryp.f[i] + rzm.f[i] + rzp.f[i] - 6.f * rc.f[i];
        op1.f[i]  = pin4.f[i] - Dc + rc.f[i] * SIXTH;
        ores.f[i] = rc.f[i] - lapD + lapR * SIXTH;
    }
    st4(p1, c, op1); st4(r1res, c, ores);
    *reinterpret_cast<float4*>(&lds[tz][ty][x0]) = ores.v;
    __syncthreads();
    int tid = (tz * 4 + ty) * 64 + tx;
    if (tid < 256) {
        int y1loc = tid >> 7, x1 = tid & 127;
        int xf = x1 << 1, yf = y1loc << 1;
        float s = lds[0][yf][xf]     + lds[0][yf][xf + 1]
                + lds[0][yf + 1][xf] + lds[0][yf + 1][xf + 1]
                + lds[1][yf][xf]     + lds[1][yf][xf + 1]
                + lds[1][yf + 1][xf] + lds[1][yf + 1][xf + 1];
        int y1 = ytile * 2 + y1loc, z1 = ztile;
        r1[(z1 * 64 + y1) * 128 + x1] = 0.125f * s;
    }
}

// K7: fused final: p2 = p1 - prol(D1) + r1res/6 (recomputed at all 7 stencil
// points), then projection + solid_body.
__global__ __launch_bounds__(256) void k_pfin(
    const float* __restrict__ p1, const float* __restrict__ rr,
    const float* __restrict__ D1,
    float* __restrict__ uIO, float* __restrict__ vIO, float* __restrict__ wIO,
    const float* __restrict__ sg,
    float* __restrict__ pout, float* __restrict__ wmg) {
    int tx = threadIdx.x, y, z;
    decode_f(blockIdx.x, y, z);
    int x0 = tx << 2, c = idx3(z, y, x0);
    int cz = z >> 1, cy = y >> 1, cx0 = tx << 1;

    const float* Drow = &D1[(cz * 64 + cy) * 128];
    float cr[4];
    cr[1] = Drow[cx0]; cr[2] = Drow[cx0 + 1];
    cr[0] = tx ? Drow[cx0 - 1] : cr[1];
    cr[3] = (tx < 63) ? Drow[cx0 + 2] : cr[2];
    int cym = y ? (y - 1) >> 1 : 0, cyp = (y < NY - 1) ? (y + 1) >> 1 : cy;
    int czm = z ? (z - 1) >> 1 : 0, czp = (z < NZ - 1) ? (z + 1) >> 1 : cz;
    float2 dym = *reinterpret_cast<const float2*>(&D1[(cz * 64 + cym) * 128 + cx0]);
    float2 dyp = *reinterpret_cast<const float2*>(&D1[(cz * 64 + cyp) * 128 + cx0]);
    float2 dzm = *reinterpret_cast<const float2*>(&D1[(czm * 64 + cy) * 128 + cx0]);
    float2 dzp = *reinterpret_cast<const float2*>(&D1[(czp * 64 + cy) * 128 + cx0]);

    F4 pc, pym, pyp, pzm, pzp;
    pc.v  = ld4(p1, z, y, x0);
    pym.v = ld4(p1, z, y > 0 ? y - 1 : 0, x0);
    pyp.v = ld4(p1, z, y < NY - 1 ? y + 1 : y, x0);
    pzm.v = ld4(p1, z > 0 ? z - 1 : 0, y, x0);
    pzp.v = ld4(p1, z < NZ - 1 ? z + 1 : z, y, x0);
    F4 rc, rym, ryp, rzm, rzp;
    rc.v  = ld4(rr, z, y, x0);
    rym.v = ld4(rr, z, y > 0 ? y - 1 : 0, x0);
    ryp.v = ld4(rr, z, y < NY - 1 ? y + 1 : y, x0);
    rzm.v = ld4(rr, z > 0 ? z - 1 : 0, y, x0);
    rzp.v = ld4(rr, z < NZ - 1 ? z + 1 : z, y, x0);
    float pxmS = tx ? p1[c - 1] : pc.f[0];
    float pxpS = (tx < 63) ? p1[c + 4] : pc.f[3];
    float rxmS = tx ? rr[c - 1] : rc.f[0];
    float rxpS = (tx < 63) ? rr[c + 4] : rc.f[3];

    F4 sc; sc.v = ld4(sg, z, y, x0);
    F4 a, b, cc;
    a.v = ld4(uIO, z, y, x0); b.v = ld4(vIO, z, y, x0); cc.v = ld4(wIO, z, y, x0);

    F4 ou, ov, ow, op, owm;
    #pragma unroll
    for (int i = 0; i < 4; i++) {
        float Dc  = cr[1 + (i >> 1)];
        float Dxm = (i == 0) ? cr[0] : cr[1 + ((i - 1) >> 1)];
        float Dxp = (i == 3) ? cr[3] : cr[1 + ((i + 1) >> 1)];
        float Dym = (i < 2) ? dym.x : dym.y;
        float Dyp = (i < 2) ? dyp.x : dyp.y;
        float Dzm = (i < 2) ? dzm.x : dzm.y;
        float Dzp = (i < 2) ? dzp.x : dzp.y;
        float pxm = i ? pc.f[i - 1] : pxmS, pxp = (i < 3) ? pc.f[i + 1] : pxpS;
        float rxm = i ? rc.f[i - 1] : rxmS, rxp = (i < 3) ? rc.f[i + 1] : rxpS;

        float p2c  = pc.f[i]  - Dc  + rc.f[i]  * SIXTH;
        float p2xm = pxm      - Dxm + rxm      * SIXTH;
        float p2xp = pxp      - Dxp + rxp      * SIXTH;
        float p2ym = pym.f[i] - Dym + rym.f[i] * SIXTH;
        float p2yp = pyp.f[i] - Dyp + ryp.f[i] * SIXTH;
        float p2zm = pzm.f[i] - Dzm + rzm.f[i] * SIXTH;
        float p2zp = pzp.f[i] - Dzp + rzp.f[i] * SIXTH;

        float dpx = 0.5f * (p2xp - p2xm);
        float dpy = 0.5f * (p2yp - p2ym);
        float dpz = 0.5f * (p2zp - p2zm);
        float inv = frcp(1.f + DT * sc.f[i]);
        ou.f[i]  = (a.f[i]  - dpx * DT) * inv;
        ov.f[i]  = (b.f[i]  - dpy * DT) * inv;
        ow.f[i]  = (cc.f[i] - dpz * DT) * inv;
        op.f[i]  = p2c;
        owm.f[i] = Dc;
    }
    st4(uIO, c, ou); st4(vIO, c, ov); st4(wIO, c, ow);
    st4(pout, c, op); st4(wmg, c, owm);
}

extern "C" void kernel_launch(void* const* d_in, const int* in_sizes, int n_in,
                              void* d_out, int out_size, void* d_ws, size_t ws_size,
                              hipStream_t stream) {
    const float* in_u  = (const float*)d_in[0];
    const float* in_v  = (const float*)d_in[1];
    const float* in_w  = (const float*)d_in[2];
    const float* in_p  = (const float*)d_in[3];
    const float* in_sg = (const float*)d_in[4];

    float* out   = (float*)d_out;
    float* O_u   = out;                      // u2 -> u_out
    float* O_v   = out + (size_t)NTOT;       // v2 -> v_out
    float* O_w   = out + (size_t)2 * NTOT;   // w2 -> w_out
    float* O_p   = out + (size_t)3 * NTOT;   // p2 (written once, by k_pfin)
    float* O_wmg = out + (size_t)4 * NTOT;   // r0 -> wmg
    float* O_r   = out + (size_t)5 * NTOT;   // final coarsest residual (512)

    float* ws  = (float*)d_ws;
    float* B0  = ws;                          // bu -> p1
    float* B1  = ws + (size_t)NTOT;           // bv -> r1res
    float* B2  = ws + (size_t)2 * NTOT;       // bw
    float* r1  = ws + (size_t)3 * NTOT;       // 262144
    float* r2  = r1 + 262144;                 // 32768
    float* r3  = r2 + 32768;                  // 4096
    float* r4w = r3 + 4096;                   // 512
    float* Dw  = r4w + 512;                   // 262144

    dim3 gF(2048);             dim3 bF(64, 4);
    dim3 gF2(1024);            dim3 bF2(64, 4, 2);
    dim3 gC(4, 4, 4);

    k_predict     <<<gF,  bF,  0, stream>>>(in_u, in_v, in_w, in_p, in_sg, B0, B1, B2);
    k_correct     <<<gF,  bF,  0, stream>>>(in_u, in_v, in_w, in_sg, B0, B1, B2, in_p,
                                            O_u, O_v, O_w);
    k_divresid_r  <<<gF2, bF2, 0, stream>>>(O_u, O_v, O_w, in_p, O_wmg /*r0*/, r1);

    // --- MG iteration 0 ---
    k_down        <<<gC, dim3(512), 0, stream>>>(r1, r2, r3, r4w);
    k_upf         <<<gC, dim3(512), 0, stream>>>(r4w, r3, r2, r1, Dw);
    k_pup_resid_r <<<gF2, bF2, 0, stream>>>(in_p, Dw, O_wmg, B0 /*p1*/, B1 /*r1res*/, r1);

    // --- MG iteration 1 ---
    k_down        <<<gC, dim3(512), 0, stream>>>(r1, r2, r3, O_r);
    k_upf         <<<gC, dim3(512), 0, stream>>>(O_r, r3, r2, r1, Dw);

    // fused p-update + projection + solid_body
    k_pfin        <<<gF, bF, 0, stream>>>(B0 /*p1*/, B1 /*r1res*/, Dw,
                                          O_u, O_v, O_w, in_sg, O_p, O_wmg);
}